// Round 11
// baseline (184.377 us; speedup 1.0000x reference)
//
#include <hip/hip_runtime.h>
#include <hip/hip_fp16.h>

#define Bx 2
#define Cx 256
#define Hx 128
#define Wx 128
#define HWx (Hx*Wx)     // 16384
#define Ox 256
#define Kx 9
#define NOFF 27         // 3*K offset-conv output channels
#define KK 2304         // 9 taps * 256 channels

typedef __attribute__((ext_vector_type(8))) _Float16 f16x8;
typedef __attribute__((ext_vector_type(4))) float f32x4;

// ws layout (float offsets):
//   tmp_t [0, 1048576)             B*HW*32  (27 used, pad 32; [b][hw][oc])
//   pscr  [1048576, 1050880)       softmax partials: pm[2*64*9], ps[1152+...]
//   stats [1050880, 1050944)       18*2 (max, 1/sum) padded
//   wbq   [1050944, 1087808)       f16 W[32][2304], k = tap*256+c
//   xtb   [1087808, 5282112)       f16 x transposed [b][hw][c] (16.8 MB)
//   wq    [5282112, 5314880)       f16 weight [o][c] (128 KB)

__device__ __forceinline__ unsigned short f2h(float f) {
    return __half_as_ushort(__float2half_rn(f));
}

// wb[oc][tap*256+c] f16 (rows 27..31 zero) from w_off[oc][c][tap]; wq[o][c] f16.
__global__ void k_prep(const float* __restrict__ w_off, const float* __restrict__ weight,
                       unsigned short* __restrict__ wb, unsigned short* __restrict__ wq) {
    int i = blockIdx.x * 256 + threadIdx.x;
    if (i < 32 * KK) {
        int oc = i / KK;
        int k  = i - oc * KK;
        int tap = k >> 8;
        int c   = k & 255;
        float v = (oc < NOFF) ? w_off[(oc * Cx + c) * 9 + tap] : 0.f;
        wb[i] = f2h(v);
    } else {
        int j = i - 32 * KK;
        if (j < Ox * Cx) wq[j] = f2h(weight[j]);
    }
}

// Transpose+convert x[b][c][hw] -> xtb[b][hw][c] f16. 64x64 tiles via LDS.
__global__ __launch_bounds__(256) void k_tr(
        const float* __restrict__ x, unsigned short* __restrict__ xtb) {
    __shared__ float tl[64][65];
    int tid = threadIdx.x;
    int hw0 = blockIdx.x * 64;
    int c0  = blockIdx.y * 64;
    int b   = blockIdx.z;
#pragma unroll
    for (int r = 0; r < 4; r++) {
        int cl = r * 16 + (tid >> 4);
        int hl = (tid & 15) * 4;
        const float4 v = *(const float4*)&x[((size_t)(b * Cx + c0 + cl)) * HWx + hw0 + hl];
        tl[cl][hl + 0] = v.x; tl[cl][hl + 1] = v.y; tl[cl][hl + 2] = v.z; tl[cl][hl + 3] = v.w;
    }
    __syncthreads();
#pragma unroll
    for (int r = 0; r < 4; r++) {
        int hl = r * 16 + (tid >> 4);
        int cl = (tid & 15) * 4;
        ushort4 o;
        o.x = f2h(tl[cl + 0][hl]); o.y = f2h(tl[cl + 1][hl]);
        o.z = f2h(tl[cl + 2][hl]); o.w = f2h(tl[cl + 3][hl]);
        *(ushort4*)&xtb[((size_t)b * HWx + hw0 + hl) * Cx + c0 + cl] = o;
    }
}

// Offset conv, all 9 taps per block, no atomics. f16 MFMA.
// Block = 64-px half-row: M=64, N=32 oc, K=2304 (4 phases x 64 ch, 9 taps).
// LDS: 3 rows x 66 slots (+-1 px halo) x 64 ch. 28.5 KB -> 2 blocks/CU.
// grid (256, B): band = &7 (XCD), sub = >>3: y = band*16 + sub/2, xh = (sub&1)*64.
__global__ __launch_bounds__(256) void k1_mfma(
        const unsigned short* __restrict__ xtb, const unsigned short* __restrict__ wb,
        const float* __restrict__ b_off, float* __restrict__ tmp_t) {
    int band = blockIdx.x & 7;
    int sub  = blockIdx.x >> 3;       // 0..31
    int y    = band * 16 + (sub >> 1);
    int xh   = (sub & 1) * 64;        // px base within row
    int b    = blockIdx.y;

    __shared__ unsigned short As[198 * 72];   // [slot = r*66 + p][64ch + 8 pad]
    int tid  = threadIdx.x;
    int wave = tid >> 6, lane = tid & 63;
    int quad = lane >> 4, col = lane & 15;

    f32x4 acc[2] = {};
    const unsigned short* xb = xtb + (size_t)b * HWx * Cx;

#pragma unroll 1
    for (int ph = 0; ph < 4; ph++) {
        __syncthreads();
        for (int u = tid; u < 1584; u += 256) {
            int slot = u >> 3;
            int ci   = (u & 7) * 8;
            int r = slot / 66;
            int p = slot - r * 66;
            int yy = y + r - 1;
            int px = xh + p - 1;
            uint4 v = make_uint4(0u, 0u, 0u, 0u);
            if (yy >= 0 && yy < Hx && px >= 0 && px < Wx)
                v = *(const uint4*)(xb + ((size_t)(yy * Wx + px)) * Cx + ph * 64 + ci);
            *(uint4*)&As[slot * 72 + ci] = v;
        }
        __syncthreads();
#pragma unroll
        for (int r = 0; r < 3; r++)
#pragma unroll
        for (int dc = 0; dc < 3; dc++)
#pragma unroll
        for (int s = 0; s < 2; s++) {
            int kl  = s * 32 + quad * 8;
            int tap = r * 3 + dc;
            int kg  = tap * 256 + ph * 64 + kl;
            int base = r * 66 + dc;
            f16x8 a  = *(const f16x8*)&As[(base + wave * 16 + col) * 72 + kl];
            f16x8 b0 = *(const f16x8*)(wb + (size_t)col * KK + kg);
            f16x8 b1 = *(const f16x8*)(wb + (size_t)(16 + col) * KK + kg);
            acc[0] = __builtin_amdgcn_mfma_f32_16x16x32_f16(a, b0, acc[0], 0, 0, 0);
            acc[1] = __builtin_amdgcn_mfma_f32_16x16x32_f16(a, b1, acc[1], 0, 0, 0);
        }
    }

    float* orow = tmp_t + ((size_t)(b * HWx) + (size_t)y * Wx + xh) * 32;
#pragma unroll
    for (int nt = 0; nt < 2; nt++) {
        int oc = nt * 16 + col;
        float bo = (oc < NOFF) ? b_off[oc] : 0.f;
#pragma unroll
        for (int r4 = 0; r4 < 4; r4++) {
            int pxd = wave * 16 + quad * 4 + r4;
            orow[(size_t)pxd * 32 + oc] = acc[nt][r4] + bo;
        }
    }
}

// Softmax phase A: per-(b,slice of 256 px): partial max & sum-exp for 9 logits.
__global__ __launch_bounds__(256) void k2a(
        const float* __restrict__ tmp_t, float* __restrict__ pscr) {
    int b  = blockIdx.y;
    int hw = blockIdx.x * 256 + threadIdx.x;
    const float* row = tmp_t + ((size_t)b * HWx + hw) * 32;
    float4 v0 = *(const float4*)(row + 16);
    float4 v1 = *(const float4*)(row + 20);
    float4 v2 = *(const float4*)(row + 24);
    float lv[9] = {v0.z, v0.w, v1.x, v1.y, v1.z, v1.w, v2.x, v2.y, v2.z};

    __shared__ float wm[4][9], wsum[4][9];
    int tid = threadIdx.x;
    int wave = tid >> 6, lane = tid & 63;

    float mx[9];
#pragma unroll
    for (int k = 0; k < 9; k++) mx[k] = lv[k];
    for (int off = 32; off > 0; off >>= 1)
#pragma unroll
        for (int k = 0; k < 9; k++) mx[k] = fmaxf(mx[k], __shfl_down(mx[k], off));
    if (lane == 0)
#pragma unroll
        for (int k = 0; k < 9; k++) wm[wave][k] = mx[k];
    __syncthreads();
    float M[9];
#pragma unroll
    for (int k = 0; k < 9; k++)
        M[k] = fmaxf(fmaxf(wm[0][k], wm[1][k]), fmaxf(wm[2][k], wm[3][k]));
    float sm[9];
#pragma unroll
    for (int k = 0; k < 9; k++) sm[k] = __expf(lv[k] - M[k]);
    for (int off = 32; off > 0; off >>= 1)
#pragma unroll
        for (int k = 0; k < 9; k++) sm[k] += __shfl_down(sm[k], off);
    if (lane == 0)
#pragma unroll
        for (int k = 0; k < 9; k++) wsum[wave][k] = sm[k];
    __syncthreads();
    if (tid < 9) {
        float S = wsum[0][tid] + wsum[1][tid] + wsum[2][tid] + wsum[3][tid];
        int idx = (b * 64 + blockIdx.x) * 9 + tid;
        pscr[idx] = M[tid];
        pscr[1152 + idx] = S;
    }
}

// Softmax phase B: merge 64 slices -> stats[bk] = (max, 1/sum). grid 18, block 64.
__global__ void k2b(const float* __restrict__ pscr, float* __restrict__ stats) {
    int bk = blockIdx.x;
    int b = bk / Kx, k = bk % Kx;
    int s = threadIdx.x;
    int idx = (b * 64 + s) * 9 + k;
    float m = pscr[idx];
    float p = pscr[1152 + idx];
    float M = m;
    for (int off = 32; off > 0; off >>= 1) M = fmaxf(M, __shfl_down(M, off));
    M = __shfl(M, 0);
    float e = p * __expf(m - M);
    for (int off = 32; off > 0; off >>= 1) e += __shfl_down(e, off);
    if (s == 0) { stats[bk * 2] = M; stats[bk * 2 + 1] = 1.f / e; }
}

// Fused sample + 1x1 conv. Block = 32 px, all 256 ch, all 256 oc. LDS 23.8 KB.
// Phase 1: bilinear sample * mask (x256 scale), packed f16 FMA, -> LDS As[32][264].
// Phase 2: MFMA GEMM M=32 px x N=256 oc x K=256 c; fused bias; float4 stores.
// grid (512, B): band = &7 (XCD), sub = >>3; px0 = (band*64+sub)*32.
__global__ __launch_bounds__(256) void k35_fused(
        const unsigned short* __restrict__ xtb, const float* __restrict__ tmp_t,
        const float* __restrict__ stats, const unsigned short* __restrict__ wq,
        const float* __restrict__ bias, float* __restrict__ out) {
    __shared__ __half2 lwh[32][36];           // (w,w) packed, x256 scale
    __shared__ unsigned short lo2[32][36];    // element offsets (hw < 16384)
    __shared__ unsigned short As[32][264];    // sampled f16, stride 132 dw
    int tid  = threadIdx.x;
    int band = blockIdx.x & 7;
    int sub  = blockIdx.x >> 3;
    int b    = blockIdx.y;
    int px0  = (band * 64 + sub) * 32;

    for (int u = tid; u < 288; u += 256) {
        int px = u / 9, k = u - px * 9;
        int hw = px0 + px;
        int y  = hw >> 7;
        int xx = hw & (Wx - 1);
        const float* trow = tmp_t + ((size_t)b * HWx + hw) * 32;
        float dy = trow[2 * k];
        float dx = trow[2 * k + 1];
        float lg = trow[18 + k];
        float m  = __expf(lg - stats[(b * Kx + k) * 2]) * stats[(b * Kx + k) * 2 + 1] * 256.f;
        float py = dy + (float)(k / 3 - 1 + y);
        float px_ = dx + (float)(k % 3 - 1 + xx);
        float fy = floorf(py), fx = floorf(px_);
        int y0 = (int)fy, x0 = (int)fx;
        float ly = py - fy, lx = px_ - fx;
        float w00 = (1.f - ly) * (1.f - lx) * m;
        float w01 = (1.f - ly) * lx * m;
        float w10 = ly * (1.f - lx) * m;
        float w11 = ly * lx * m;
        int y1 = y0 + 1, x1 = x0 + 1;
        bool vy0 = (y0 >= 0) & (y0 < Hx), vy1 = (y1 >= 0) & (y1 < Hx);
        bool vx0 = (x0 >= 0) & (x0 < Wx), vx1 = (x1 >= 0) & (x1 < Wx);
        int cy0 = min(max(y0, 0), Hx - 1), cy1 = min(max(y1, 0), Hx - 1);
        int cx0 = min(max(x0, 0), Wx - 1), cx1 = min(max(x1, 0), Wx - 1);
        float a00 = (vy0 && vx0) ? w00 : 0.f;
        float a01 = (vy0 && vx1) ? w01 : 0.f;
        float a10 = (vy1 && vx0) ? w10 : 0.f;
        float a11 = (vy1 && vx1) ? w11 : 0.f;
        lwh[px][4 * k + 0] = __half2half2(__float2half_rn(a00));  lo2[px][4 * k + 0] = (unsigned short)(cy0 * Wx + cx0);
        lwh[px][4 * k + 1] = __half2half2(__float2half_rn(a01));  lo2[px][4 * k + 1] = (unsigned short)(cy0 * Wx + cx1);
        lwh[px][4 * k + 2] = __half2half2(__float2half_rn(a10));  lo2[px][4 * k + 2] = (unsigned short)(cy1 * Wx + cx0);
        lwh[px][4 * k + 3] = __half2half2(__float2half_rn(a11));  lo2[px][4 * k + 3] = (unsigned short)(cy1 * Wx + cx1);
    }
    __syncthreads();

    int wave = tid >> 6;
    int lane = tid & 63;
    int half = lane >> 5;
    int li   = lane & 31;
    const unsigned short* xb = xtb + (size_t)b * HWx * Cx + li * 8;
    const __half2 uns = __half2half2(__float2half_rn(1.f / 256.f));
#pragma unroll 1
    for (int pass = 0; pass < 4; pass++) {
        int px = wave * 8 + pass * 2 + half;
        __half2 a0 = __half2half2(__ushort_as_half(0));
        __half2 a1 = a0, a2 = a0, a3 = a0;
#pragma unroll
        for (int j = 0; j < 36; j++) {
            __half2 w = lwh[px][j];
            int   off = lo2[px][j];
            uint4 v = *(const uint4*)(xb + (size_t)off * Cx);
            a0 = __hfma2(w, *(__half2*)&v.x, a0);
            a1 = __hfma2(w, *(__half2*)&v.y, a1);
            a2 = __hfma2(w, *(__half2*)&v.z, a2);
            a3 = __hfma2(w, *(__half2*)&v.w, a3);
        }
        a0 = __hmul2(a0, uns); a1 = __hmul2(a1, uns);
        a2 = __hmul2(a2, uns); a3 = __hmul2(a3, uns);
        uint4 r;
        r.x = *(unsigned*)&a0; r.y = *(unsigned*)&a1;
        r.z = *(unsigned*)&a2; r.w = *(unsigned*)&a3;
        *(uint4*)&As[px][li * 8] = r;
    }
    __syncthreads();

    // GEMM: wave covers oc [wave*64, wave*64+64), all 32 px.
    int quad = lane >> 4, col = lane & 15;
    f32x4 acc[2][4] = {};
#pragma unroll
    for (int ki = 0; ki < 8; ki++) {
        int k0 = ki * 32;
        f16x8 a[2], w[4];
#pragma unroll
        for (int mt = 0; mt < 2; mt++)
            a[mt] = *(const f16x8*)&As[mt * 16 + col][k0 + quad * 8];
#pragma unroll
        for (int nt = 0; nt < 4; nt++)
            w[nt] = *(const f16x8*)(wq + (size_t)(wave * 64 + nt * 16 + col) * Cx + k0 + quad * 8);
#pragma unroll
        for (int mt = 0; mt < 2; mt++)
#pragma unroll
            for (int nt = 0; nt < 4; nt++)
                acc[mt][nt] = __builtin_amdgcn_mfma_f32_16x16x32_f16(a[mt], w[nt], acc[mt][nt], 0, 0, 0);
    }

#pragma unroll
    for (int nt = 0; nt < 4; nt++) {
        int oc = wave * 64 + nt * 16 + col;
        float bo = bias[oc];
#pragma unroll
        for (int mt = 0; mt < 2; mt++) {
            int hw = px0 + mt * 16 + quad * 4;
            float4 v;
            v.x = acc[mt][nt][0] + bo; v.y = acc[mt][nt][1] + bo;
            v.z = acc[mt][nt][2] + bo; v.w = acc[mt][nt][3] + bo;
            *(float4*)&out[((size_t)(b * Ox + oc)) * HWx + hw] = v;
        }
    }
}

extern "C" void kernel_launch(void* const* d_in, const int* in_sizes, int n_in,
                              void* d_out, int out_size, void* d_ws, size_t ws_size,
                              hipStream_t stream) {
    const float*    x      = (const float*)d_in[0];
    const float*    w_off  = (const float*)d_in[1];
    const float*    b_off  = (const float*)d_in[2];
    const float*    weight = (const float*)d_in[3];
    const float*    bias   = (const float*)d_in[4];
    float* out = (float*)d_out;
    float* ws  = (float*)d_ws;

    float*          tmp_t = ws;
    float*          pscr  = ws + 1048576;
    float*          stats = ws + 1050880;
    unsigned short* wbq   = (unsigned short*)(ws + 1050944);
    unsigned short* xtb   = (unsigned short*)(ws + 1087808);
    unsigned short* wq    = (unsigned short*)(ws + 5282112);

    k_prep<<<dim3(544), 256, 0, stream>>>(w_off, weight, wbq, wq);
    k_tr<<<dim3(HWx / 64, Cx / 64, Bx), 256, 0, stream>>>(x, xtb);
    k1_mfma<<<dim3(256, Bx), 256, 0, stream>>>(xtb, wbq, b_off, tmp_t);
    k2a<<<dim3(64, Bx), 256, 0, stream>>>(tmp_t, pscr);
    k2b<<<dim3(Bx * Kx), 64, 0, stream>>>(pscr, stats);
    k35_fused<<<dim3(512, Bx), 256, 0, stream>>>(xtb, tmp_t, stats, wq, bias, out);
}